// Round 1
// baseline (3191.072 us; speedup 1.0000x reference)
//
#include <hip/hip_runtime.h>
#include <hip/hip_bf16.h>

#define NB 4
#define NPTS 8192
#define CIN 32
#define COUT 64
#define MOUT 2048   // NPTS / STRIDE
#define KNN 16
#define EPSBN 1e-5f

// ---------------------------------------------------------------------------
// Setup: fold BN into conv weights.  w1s[o][c] = w1[o][c]*a1[o], c1[o]=b1-m1*a1
// wbuf layout (floats): [0,2240) w1s | [2240,2304) c1 | [2304,6400) w2s | [6400,6464) c2
// ---------------------------------------------------------------------------
__global__ void setup_kernel(const float* __restrict__ w1, const float* __restrict__ g1,
                             const float* __restrict__ b1, const float* __restrict__ m1,
                             const float* __restrict__ v1, const float* __restrict__ w2,
                             const float* __restrict__ g2, const float* __restrict__ b2,
                             const float* __restrict__ m2, const float* __restrict__ v2,
                             float* __restrict__ wbuf) {
    int o = threadIdx.x;
    if (o >= 64) return;
    float a1 = g1[o] * rsqrtf(v1[o] + EPSBN);
    wbuf[2240 + o] = b1[o] - m1[o] * a1;
    for (int c = 0; c < 35; ++c) wbuf[o * 35 + c] = w1[o * 35 + c] * a1;
    float a2 = g2[o] * rsqrtf(v2[o] + EPSBN);
    wbuf[6400 + o] = b2[o] - m2[o] * a2;
    for (int c = 0; c < 64; ++c) wbuf[2304 + o * 64 + c] = w2[o * 64 + c] * a2;
}

// ---------------------------------------------------------------------------
// Transpose x (B,C,N) -> xt (B,N,C) with LDS tiles (coalesced both sides)
// ---------------------------------------------------------------------------
__global__ __launch_bounds__(256) void transpose_kernel(const float* __restrict__ x,
                                                        float* __restrict__ xt) {
    __shared__ float tile[CIN][65];
    int b = blockIdx.y;
    int n0 = blockIdx.x * 64;
    int tid = threadIdx.x;
#pragma unroll
    for (int r = 0; r < 8; ++r) {
        int i = r * 256 + tid;
        int c = i >> 6, n = i & 63;
        tile[c][n] = x[((size_t)b * CIN + c) * NPTS + n0 + n];
    }
    __syncthreads();
#pragma unroll
    for (int r = 0; r < 8; ++r) {
        int i = r * 256 + tid;
        int n = i >> 5, c = i & 31;
        xt[((size_t)b * NPTS + n0 + n) * CIN + c] = tile[c][n];
    }
}

// ---------------------------------------------------------------------------
// FPS: one block per batch, 256 threads, 32 points/thread in registers.
// Replicates XLA arithmetic exactly: d = (dx*dx + dy*dy) + dz*dz with
// NO fp contraction (__fmul_rn/__fadd_rn), argmax = first occurrence of max.
// Writes p2 (B,M,3) directly.
// ---------------------------------------------------------------------------
#define FPS_PT 32
__global__ __launch_bounds__(256) void fps_kernel(const float* __restrict__ p1,
                                                  float* __restrict__ p2out) {
    int b = blockIdx.x;
    int tid = threadIdx.x;
    int lane = tid & 63, wv = tid >> 6;
    const float* P = p1 + (size_t)b * NPTS * 3;

    float px[FPS_PT], py[FPS_PT], pz[FPS_PT], dmin[FPS_PT];
    int base = tid * FPS_PT;
#pragma unroll
    for (int s = 0; s < FPS_PT; ++s) {
        int j = base + s;
        px[s] = P[j * 3 + 0];
        py[s] = P[j * 3 + 1];
        pz[s] = P[j * 3 + 2];
        dmin[s] = 1e10f;
    }

    __shared__ float sval[2][4];
    __shared__ int   sidx[2][4];

    float lx = P[0], ly = P[1], lz = P[2];
    if (tid == 0) {
        p2out[(size_t)(b * MOUT) * 3 + 0] = lx;
        p2out[(size_t)(b * MOUT) * 3 + 1] = ly;
        p2out[(size_t)(b * MOUT) * 3 + 2] = lz;
    }

    for (int m = 1; m < MOUT; ++m) {
        float bv = -1.0f;
        int bi = 0;
#pragma unroll
        for (int s = 0; s < FPS_PT; ++s) {
            float dx = __fsub_rn(px[s], lx);
            float dy = __fsub_rn(py[s], ly);
            float dz = __fsub_rn(pz[s], lz);
            float d = __fadd_rn(__fadd_rn(__fmul_rn(dx, dx), __fmul_rn(dy, dy)),
                                __fmul_rn(dz, dz));
            float nd = fminf(dmin[s], d);
            dmin[s] = nd;
            if (nd > bv) { bv = nd; bi = base + s; }   // strict > : first max
        }
        // wave butterfly argmax, ties -> smaller index
#pragma unroll
        for (int off = 32; off >= 1; off >>= 1) {
            float ov = __shfl_xor(bv, off);
            int   oi = __shfl_xor(bi, off);
            if (ov > bv || (ov == bv && oi < bi)) { bv = ov; bi = oi; }
        }
        int par = m & 1;
        if (lane == 0) { sval[par][wv] = bv; sidx[par][wv] = bi; }
        __syncthreads();
        float gv = sval[par][0];
        int   gi = sidx[par][0];
#pragma unroll
        for (int w = 1; w < 4; ++w) {
            float vv = sval[par][w];
            int   ii = sidx[par][w];
            if (vv > gv || (vv == gv && ii < gi)) { gv = vv; gi = ii; }
        }
        int widx = __builtin_amdgcn_readfirstlane(gi);
        lx = P[widx * 3 + 0];
        ly = P[widx * 3 + 1];
        lz = P[widx * 3 + 2];
        if (tid == 0) {
            p2out[((size_t)b * MOUT + m) * 3 + 0] = lx;
            p2out[((size_t)b * MOUT + m) * 3 + 1] = ly;
            p2out[((size_t)b * MOUT + m) * 3 + 2] = lz;
        }
    }
}

// ---------------------------------------------------------------------------
// kNN: one wave per query. Distributed sorted top-16 in lanes 0..15,
// ballot-compacted insertion (no per-lane divergent insertion sort).
// d2 mirrors reference formula: (s2[m]+s1[n]) - 2*dot  (no contraction).
// ---------------------------------------------------------------------------
__global__ __launch_bounds__(256) void knn_kernel(const float* __restrict__ p1,
                                                  const float* __restrict__ p2,
                                                  int* __restrict__ nnout) {
    int tid = threadIdx.x;
    int lane = tid & 63, wid = tid >> 6;
    int qid = blockIdx.x * 4 + wid;          // 0..8191
    int b = qid >> 11;
    const float* Pb = p1 + (size_t)b * NPTS * 3;
    const float* q = p2 + (size_t)qid * 3;
    float qx = q[0], qy = q[1], qz = q[2];
    float s2q = __fadd_rn(__fadd_rn(__fmul_rn(qx, qx), __fmul_rn(qy, qy)),
                          __fmul_rn(qz, qz));

    float tval = 3.0e38f;   // distributed sorted list (lanes 0..15)
    int   tidx = -1;
    float tau = 3.0e38f;

    for (int n0 = 0; n0 < NPTS; n0 += 64) {
        int n = n0 + lane;
        const float* pp = Pb + n * 3;
        float px = pp[0], py = pp[1], pz = pp[2];
        float s1n = __fadd_rn(__fadd_rn(__fmul_rn(px, px), __fmul_rn(py, py)),
                              __fmul_rn(pz, pz));
        float dot = __fadd_rn(__fadd_rn(__fmul_rn(qx, px), __fmul_rn(qy, py)),
                              __fmul_rn(qz, pz));
        float d2 = __fsub_rn(__fadd_rn(s2q, s1n), __fmul_rn(2.0f, dot));

        unsigned long long act = __ballot(d2 < tau);
        while (act) {
            int l = __ffsll(act) - 1;
            float dd = __shfl(d2, l);
            int   nn_ = __shfl(n, l);
            unsigned long long mle = __ballot(lane < 16 && tval <= dd);
            int pos = __popcll(mle);                 // stable insert position
            float sv = __shfl_up(tval, 1);
            int   si = __shfl_up(tidx, 1);
            if (lane < 16) {
                if (lane == pos)      { tval = dd; tidx = nn_; }
                else if (lane > pos)  { tval = sv; tidx = si; }
            }
            tau = __shfl(tval, 15);
            act &= (act - 1);
            act &= __ballot(d2 < tau);
        }
    }
    if (lane < 16) nnout[(size_t)qid * KNN + lane] = tidx;
}

// ---------------------------------------------------------------------------
// Fused gather + conv1(BN-folded)+ReLU + conv2(BN-folded)+ReLU + max over K.
// Lane = (query-in-wave qq, neighbor k). Weights via uniform scalar loads.
// ---------------------------------------------------------------------------
template <int XT>
__global__ __launch_bounds__(256) void conv_kernel(const float* __restrict__ p1,
                                                   const float* __restrict__ p2,
                                                   const float* __restrict__ xsrc,
                                                   const int* __restrict__ nn,
                                                   const float* __restrict__ wbuf,
                                                   float* __restrict__ y) {
    const float* w1s = wbuf;
    const float* c1s = wbuf + 2240;
    const float* w2s = wbuf + 2304;
    const float* c2s = wbuf + 6400;
    int tid = threadIdx.x;
    int lane = tid & 63, wid = tid >> 6;
    int qq = lane >> 4, k = lane & 15;
    int qid = (blockIdx.x * 4 + wid) * 4 + qq;   // 0..8191
    int b = qid >> 11, m = qid & 2047;
    int nk = nn[(size_t)qid * KNN + k];

    const float* qp = p2 + (size_t)qid * 3;
    const float* np = p1 + ((size_t)b * NPTS + nk) * 3;
    float h[35];
    h[0] = np[0] - qp[0];
    h[1] = np[1] - qp[1];
    h[2] = np[2] - qp[2];
    if (XT) {
        const float4* xr = (const float4*)(xsrc + ((size_t)b * NPTS + nk) * CIN);
#pragma unroll
        for (int q8 = 0; q8 < 8; ++q8) {
            float4 f = xr[q8];
            h[3 + q8 * 4 + 0] = f.x;
            h[3 + q8 * 4 + 1] = f.y;
            h[3 + q8 * 4 + 2] = f.z;
            h[3 + q8 * 4 + 3] = f.w;
        }
    } else {
#pragma unroll
        for (int c = 0; c < CIN; ++c)
            h[3 + c] = xsrc[((size_t)b * CIN + c) * NPTS + nk];
    }

    float acc2[64];
#pragma unroll
    for (int o2 = 0; o2 < 64; ++o2) acc2[o2] = c2s[o2];

    for (int o = 0; o < 64; ++o) {            // dynamic loop: t1 streamed as scalar
        float a = c1s[o];
#pragma unroll
        for (int c = 0; c < 35; ++c) a = fmaf(h[c], w1s[o * 35 + c], a);
        a = fmaxf(a, 0.0f);
#pragma unroll
        for (int o2 = 0; o2 < 64; ++o2) acc2[o2] = fmaf(a, w2s[o2 * 64 + o], acc2[o2]);
    }

#pragma unroll
    for (int o2 = 0; o2 < 64; ++o2) {
        float v = fmaxf(acc2[o2], 0.0f);
        v = fmaxf(v, __shfl_xor(v, 8));
        v = fmaxf(v, __shfl_xor(v, 4));
        v = fmaxf(v, __shfl_xor(v, 2));
        v = fmaxf(v, __shfl_xor(v, 1));
        if ((lane & 15) == (o2 & 15))
            y[((size_t)b * COUT + o2) * MOUT + m] = v;
    }
}

// ---------------------------------------------------------------------------
extern "C" void kernel_launch(void* const* d_in, const int* in_sizes, int n_in,
                              void* d_out, int out_size, void* d_ws, size_t ws_size,
                              hipStream_t stream) {
    const float* p1 = (const float*)d_in[0];
    const float* x  = (const float*)d_in[1];
    const float* w1 = (const float*)d_in[2];
    const float* g1 = (const float*)d_in[3];
    const float* b1 = (const float*)d_in[4];
    const float* m1 = (const float*)d_in[5];
    const float* v1 = (const float*)d_in[6];
    const float* w2 = (const float*)d_in[7];
    const float* g2 = (const float*)d_in[8];
    const float* b2 = (const float*)d_in[9];
    const float* m2 = (const float*)d_in[10];
    const float* v2 = (const float*)d_in[11];

    float* p2o = (float*)d_out;                       // (B,M,3)
    float* yo  = p2o + (size_t)NB * MOUT * 3;         // (B,COUT,M)

    char* ws = (char*)d_ws;
    int*   nn   = (int*)ws;                            // 512 KiB
    float* wbuf = (float*)(ws + 512 * 1024);           // 25.9 KiB
    float* xt   = (float*)(ws + 1024 * 1024);          // 4 MiB
    bool use_xt = ws_size >= (size_t)(1024 * 1024) + (size_t)NB * NPTS * CIN * 4;

    setup_kernel<<<1, 64, 0, stream>>>(w1, g1, b1, m1, v1, w2, g2, b2, m2, v2, wbuf);
    if (use_xt)
        transpose_kernel<<<dim3(NPTS / 64, NB), 256, 0, stream>>>(x, xt);
    fps_kernel<<<NB, 256, 0, stream>>>(p1, p2o);
    knn_kernel<<<(NB * MOUT) / 4, 256, 0, stream>>>(p1, p2o, nn);
    if (use_xt)
        conv_kernel<1><<<(NB * MOUT) / 16, 256, 0, stream>>>(p1, p2o, xt, nn, wbuf, yo);
    else
        conv_kernel<0><<<(NB * MOUT) / 16, 256, 0, stream>>>(p1, p2o, x, nn, wbuf, yo);
}